// Round 15
// baseline (9925.594 us; speedup 1.0000x reference)
//
#include <hip/hip_runtime.h>

// LSTM 2-layer, S=512 B=64 IN=H=1024, fp32 I/O, fp16 MFMA compute.
// R15: LAYER-SPLIT GRID. 512 wgs x 256 thr (2 wgs/CU, co-resident:
//   LDS worst 2x65KB=130KB<160KB, VGPR 132 -> capacity >= 2/CU everywhere).
//   wgs 0-255: layer0 only (rounds k=0..511): wv0/1 x-GEMM (dep-free),
//     wv2/3 h0-GEMM (epoch0-gated); sync; ew on ALL 4 waves (1 out/thread,
//     col=wv); h0 store sc0|sc1; drain; sync; flag0=k+1.
//   wgs 256-511: layer1 (rounds k=1..512, t1=k-1): wv0/1 h0-input GEMM
//     (epoch0>=k), wv2/3 h1-GEMM (epoch1>=k-1); sync; ew; h1+out stores;
//     drain; sync; flag1=k.
//   One phase per round per wg; the layers' phases run CONCURRENTLY.
//   Aggregators (consumer-side, no prior-phase lag): wg256/wv0 polls flags0
//   and publishes epoch0 (poll == its own wait); wg257/wv2 ditto epoch1.
// Carried over verified: asm-MLP 32-flight GEMM banks (R14), frag-ordered
// weight LDS (R12), sc0|sc1 h rings + relaxed flags + no fences (R3+),
// h0ring may alias d_out upper half; out[511] deferred past epoch1=512
// (alias re-derived for this schedule: 2s+2 <= 256+s for s<=254, s=255 deferred).

#define SEQ   512
#define BATCH 64
#define HID   1024
#define NG    4096
#define KCAT  2048
#define F0_BASE 0            // flags0: + wg'*32
#define E0_IDX  8192         // epoch0 replicas: + (wg'&31)*32
#define F1_BASE 16384        // flags1: + wg'*32
#define E1_IDX  24576        // epoch1 replicas: + (wg'&31)*32

// dynamic LDS (bytes), uniform for both layers:
//   [0,49152)       weight frag regions (layer0 uses 2x16KB, layer1 3x16KB)
//   [49152,66560)   accL: float[4][64][17]
#define ACC_OFF  49152
#define SMEM_BYTES 66560

typedef __attribute__((ext_vector_type(8))) _Float16 f16x8;
typedef __attribute__((ext_vector_type(4))) float    f32x4;

__device__ __forceinline__ float sigm_f(float x){ return 1.f/(1.f + __expf(-x)); }
__device__ __forceinline__ float tanh_f(float x){
    float e = __expf(-2.f*fabsf(x));
    float r = (1.f - e)/(1.f + e);
    return copysignf(r, x);
}

// 2B write-through store (h elements; 1 per thread)
__device__ __forceinline__ void store_h2(_Float16* p, unsigned v){
    asm volatile("global_store_short %0, %1, off sc0 sc1" :: "v"(p), "v"(v) : "memory");
}
__device__ __forceinline__ void drain_vmem(){
    asm volatile("s_waitcnt vmcnt(0)" ::: "memory");
}

// ---- ordered asm loads (R14-verified) ----
#define GLD(dst, base, OFF) \
    asm volatile("global_load_dwordx4 %0, %1, off offset:" #OFF \
                 : "=&v"(dst) : "v"(base))
#define GLD8L(arr, i, B) \
    GLD(arr[(i)+0],B,0);   GLD(arr[(i)+1],B,64);  GLD(arr[(i)+2],B,128); GLD(arr[(i)+3],B,192); \
    GLD(arr[(i)+4],B,256); GLD(arr[(i)+5],B,320); GLD(arr[(i)+6],B,384); GLD(arr[(i)+7],B,448)
#define GLD8H(arr, i, B) \
    GLD(arr[(i)+0],B,512); GLD(arr[(i)+1],B,576); GLD(arr[(i)+2],B,640); GLD(arr[(i)+3],B,704); \
    GLD(arr[(i)+4],B,768); GLD(arr[(i)+5],B,832); GLD(arr[(i)+6],B,896); GLD(arr[(i)+7],B,960)
#define VMWAIT0 \
    asm volatile("s_waitcnt vmcnt(0)" ::: "memory"); \
    __builtin_amdgcn_sched_barrier(0)

// ---------------- prep kernels (unchanged) ----------------

__global__ void prep_w_kernel(const float* __restrict__ Wx, const float* __restrict__ Wh,
                              const float* __restrict__ bx, const float* __restrict__ bh,
                              _Float16* __restrict__ Wr, float* __restrict__ br){
    int p = blockIdx.x;
    int j = p >> 2, g = p & 3;
    int r = g*1024 + j;
    int k = threadIdx.x * 8;
    const float* s = (k < 1024) ? (Wx + (size_t)r*1024 + k)
                                : (Wh + (size_t)r*1024 + (k - 1024));
    float4 v0 = *reinterpret_cast<const float4*>(s);
    float4 v1 = *reinterpret_cast<const float4*>(s + 4);
    f16x8 o;
    o[0]=(_Float16)v0.x; o[1]=(_Float16)v0.y; o[2]=(_Float16)v0.z; o[3]=(_Float16)v0.w;
    o[4]=(_Float16)v1.x; o[5]=(_Float16)v1.y; o[6]=(_Float16)v1.z; o[7]=(_Float16)v1.w;
    *reinterpret_cast<f16x8*>(Wr + (size_t)p*KCAT + k) = o;
    if (threadIdx.x == 0) br[p] = bx[r] + bh[r];
}

__global__ void prep_x_kernel(const float* __restrict__ x, _Float16* xo){
    size_t i = ((size_t)blockIdx.x*256 + threadIdx.x) * 8;
    float4 v0 = *reinterpret_cast<const float4*>(x + i);
    float4 v1 = *reinterpret_cast<const float4*>(x + i + 4);
    f16x8 o;
    o[0]=(_Float16)v0.x; o[1]=(_Float16)v0.y; o[2]=(_Float16)v0.z; o[3]=(_Float16)v0.w;
    o[4]=(_Float16)v1.x; o[5]=(_Float16)v1.y; o[6]=(_Float16)v1.z; o[7]=(_Float16)v1.w;
    *reinterpret_cast<f16x8*>(xo + i) = o;
}

__global__ void init_misc_kernel(int* flags, _Float16* hz){
    int i = blockIdx.x*256 + threadIdx.x;            // 32768 threads
    flags[i] = 0;
    if (i < 16384){
        typedef __attribute__((ext_vector_type(4))) _Float16 f16x4;
        f16x4 z; z[0]=(_Float16)0.f; z[1]=(_Float16)0.f; z[2]=(_Float16)0.f; z[3]=(_Float16)0.f;
        *reinterpret_cast<f16x4*>(hz + (size_t)i*4) = z;
    }
}

// ---------------- sync helpers (no fences) ----------------

__device__ __forceinline__ void wait_epoch_g(const int* flags, int eidx, int k, int rep){
    for(;;){
        int e = __hip_atomic_load(&flags[eidx + rep*32], __ATOMIC_RELAXED, __HIP_MEMORY_SCOPE_AGENT);
        if (e >= k) break;
        __builtin_amdgcn_s_sleep(2);
    }
    asm volatile("" ::: "memory");
}

__device__ __forceinline__ void aggregate_publish(int* flags, int base, int eidx,
                                                  int k, int lane){
    const int b = lane*4;
    for(;;){
        int a0 = __hip_atomic_load(&flags[base + (b+0)*32], __ATOMIC_RELAXED, __HIP_MEMORY_SCOPE_AGENT);
        int a1 = __hip_atomic_load(&flags[base + (b+1)*32], __ATOMIC_RELAXED, __HIP_MEMORY_SCOPE_AGENT);
        int a2 = __hip_atomic_load(&flags[base + (b+2)*32], __ATOMIC_RELAXED, __HIP_MEMORY_SCOPE_AGENT);
        int a3 = __hip_atomic_load(&flags[base + (b+3)*32], __ATOMIC_RELAXED, __HIP_MEMORY_SCOPE_AGENT);
        bool ok = (a0>=k) && (a1>=k) && (a2>=k) && (a3>=k);
        if (__all(ok)) break;
        __builtin_amdgcn_s_sleep(1);
    }
    asm volatile("" ::: "memory");
    if (lane < 32)
        __hip_atomic_store(&flags[eidx + lane*32], k, __ATOMIC_RELAXED, __HIP_MEMORY_SCOPE_AGENT);
}

// ---------------- GEMM helpers (R14-verified) ----------------

__device__ __forceinline__ f32x4 mfma16(f16x8 a, f16x8 b, f32x4 c){
    return __builtin_amdgcn_mfma_f32_16x16x32_f16(a, b, c, 0, 0, 0);
}

// A via asm loads, 32-flight banks, vmcnt(0); B from frag-ordered LDS.
__device__ __forceinline__ void gemm_asm_ldsb(const _Float16* A, const char* wfrag,
                                              f32x4* acc){
    const _Float16* b0 = A;
    const _Float16* b1 = A + 16*1024;
    const _Float16* b2 = A + 32*1024;
    const _Float16* b3 = A + 48*1024;
    f16x8 a[32];
    __builtin_amdgcn_sched_barrier(0);
    GLD8L(a, 0, b0); GLD8L(a, 8, b1); GLD8L(a, 16, b2); GLD8L(a, 24, b3);
    VMWAIT0;
    #pragma unroll
    for (int kk = 0; kk < 8; ++kk){
        f16x8 bb = *reinterpret_cast<const f16x8*>(wfrag + kk*1024);
        acc[0] = mfma16(a[kk],      bb, acc[0]);
        acc[1] = mfma16(a[8 + kk],  bb, acc[1]);
        acc[2] = mfma16(a[16 + kk], bb, acc[2]);
        acc[3] = mfma16(a[24 + kk], bb, acc[3]);
    }
    __builtin_amdgcn_sched_barrier(0);
    GLD8H(a, 0, b0); GLD8H(a, 8, b1); GLD8H(a, 16, b2); GLD8H(a, 24, b3);
    VMWAIT0;
    #pragma unroll
    for (int kk = 0; kk < 8; ++kk){
        f16x8 bb = *reinterpret_cast<const f16x8*>(wfrag + (8 + kk)*1024);
        acc[0] = mfma16(a[kk],      bb, acc[0]);
        acc[1] = mfma16(a[8 + kk],  bb, acc[1]);
        acc[2] = mfma16(a[16 + kk], bb, acc[2]);
        acc[3] = mfma16(a[24 + kk], bb, acc[3]);
    }
    __builtin_amdgcn_sched_barrier(0);
}

// A + B via asm loads (B from global, L2-resident weights).
__device__ __forceinline__ void gemm_asm_gb(const _Float16* A, const _Float16* Wp,
                                            f32x4* acc){
    const _Float16* b0 = A;
    const _Float16* b1 = A + 16*1024;
    const _Float16* b2 = A + 32*1024;
    const _Float16* b3 = A + 48*1024;
    f16x8 bw[8], a[32];
    __builtin_amdgcn_sched_barrier(0);
    GLD8L(bw, 0, Wp);
    GLD8L(a, 0, b0); GLD8L(a, 8, b1); GLD8L(a, 16, b2); GLD8L(a, 24, b3);
    VMWAIT0;
    #pragma unroll
    for (int kk = 0; kk < 8; ++kk){
        acc[0] = mfma16(a[kk],      bw[kk], acc[0]);
        acc[1] = mfma16(a[8 + kk],  bw[kk], acc[1]);
        acc[2] = mfma16(a[16 + kk], bw[kk], acc[2]);
        acc[3] = mfma16(a[24 + kk], bw[kk], acc[3]);
    }
    __builtin_amdgcn_sched_barrier(0);
    GLD8H(bw, 0, Wp);
    GLD8H(a, 0, b0); GLD8H(a, 8, b1); GLD8H(a, 16, b2); GLD8H(a, 24, b3);
    VMWAIT0;
    #pragma unroll
    for (int kk = 0; kk < 8; ++kk){
        acc[0] = mfma16(a[kk],      bw[kk], acc[0]);
        acc[1] = mfma16(a[8 + kk],  bw[kk], acc[1]);
        acc[2] = mfma16(a[16 + kk], bw[kk], acc[2]);
        acc[3] = mfma16(a[24 + kk], bw[kk], acc[3]);
    }
    __builtin_amdgcn_sched_barrier(0);
}

// f32 x fallback
__device__ __forceinline__ void gemm_q_f32(const float* A, const _Float16* Wp, f32x4* acc){
    #pragma unroll 2
    for (int kk = 0; kk < 16; ++kk){
        f16x8 b = *reinterpret_cast<const f16x8*>(Wp + kk*32);
        f16x8 a[4];
        #pragma unroll
        for (int m = 0; m < 4; ++m){
            float4 u0 = *reinterpret_cast<const float4*>(A + kk*32 + (size_t)m*16*1024);
            float4 u1 = *reinterpret_cast<const float4*>(A + kk*32 + (size_t)m*16*1024 + 4);
            f16x8 v;
            v[0]=(_Float16)u0.x; v[1]=(_Float16)u0.y; v[2]=(_Float16)u0.z; v[3]=(_Float16)u0.w;
            v[4]=(_Float16)u1.x; v[5]=(_Float16)u1.y; v[6]=(_Float16)u1.z; v[7]=(_Float16)u1.w;
            a[m] = v;
        }
        acc[0] = mfma16(a[0], b, acc[0]);
        acc[1] = mfma16(a[1], b, acc[1]);
        acc[2] = mfma16(a[2], b, acc[2]);
        acc[3] = mfma16(a[3], b, acc[3]);
    }
}

// ---------------- persistent LSTM kernel ----------------

__global__ __launch_bounds__(256, 1)
void lstm_persist(const _Float16* __restrict__ Wr0, const _Float16* __restrict__ Wr1,
                  const float* __restrict__ br0, const float* __restrict__ br1,
                  const _Float16* __restrict__ xbf, const float* __restrict__ xf32,
                  int use_xf16, const _Float16* __restrict__ hz,
                  _Float16* h0ring, _Float16* h1ring, float* out, int* flags){
    extern __shared__ char smem[];
    float (*accL)[64][17] = reinterpret_cast<float(*)[64][17]>(smem + ACC_OFF);

    const int tid   = threadIdx.x;
    const int wgid  = blockIdx.x;          // 0..511
    const int layer = wgid >> 8;           // 0 or 1
    const int wgl   = wgid & 255;
    const int wv    = tid >> 6;
    const int lane  = tid & 63;
    const int r     = lane & 15;
    const int q     = lane >> 4;
    const int p0    = wgl * 16;
    const int rep   = wgl & 31;
    const size_t BH = (size_t)BATCH*HID;

    // ---- stage recurrent weights, frag-ordered ----
    if (layer == 0){
        for (int idx = tid; idx < 2048; idx += 256){   // Wr0 cols 1024..2047
            int wvh = idx >> 10, kk = (idx >> 6) & 15, ln = idx & 63;
            const _Float16* s = Wr0 + (size_t)(p0 + (ln & 15))*KCAT + 1024
                                + wvh*512 + kk*32 + (ln >> 4)*8;
            *reinterpret_cast<f16x8*>(smem + idx*16) = *reinterpret_cast<const f16x8*>(s);
        }
    } else {
        for (int idx = tid; idx < 3072; idx += 256){   // Wr1 cols 512..2047
            int wvd = idx >> 10, kk = (idx >> 6) & 15, ln = idx & 63;
            const _Float16* s = Wr1 + (size_t)(p0 + (ln & 15))*KCAT + 512
                                + wvd*512 + kk*32 + (ln >> 4)*8;
            *reinterpret_cast<f16x8*>(smem + idx*16) = *reinterpret_cast<const f16x8*>(s);
        }
    }
    __syncthreads();

    const int kofs = (wv & 1)*512 + q*8;   // A k-offset within its 1024-half
    const int wcol = wv*512 + q*8;         // global-weight column (layer0 wv0/1; layer1 wv0)
    float cst = 0.f, ho_keep = 0.f;
    f32x4 bias = *reinterpret_cast<const f32x4*>(&(layer ? br1 : br0)[p0 + wv*4]);

    if (layer == 0){
        // ==================== LAYER 0 ====================
        const char* wfrag = smem + (wv >= 2 ? (wv-2)*16384 : 0) + lane*16;
        for (int k = 0; k < SEQ; ++k){
            f32x4 acc[4];
            #pragma unroll
            for (int m = 0; m < 4; ++m){ acc[m].x=0;acc[m].y=0;acc[m].z=0;acc[m].w=0; }

            if (wv < 2){
                if (use_xf16)
                    gemm_asm_gb(xbf + (size_t)k*BH + (size_t)r*HID + kofs,
                                Wr0 + (size_t)(p0 + r)*KCAT + wcol, acc);
                else
                    gemm_q_f32(xf32 + (size_t)k*BH + (size_t)r*HID + kofs,
                               Wr0 + (size_t)(p0 + r)*KCAT + wcol, acc);
            } else {
                if (k > 0) wait_epoch_g(flags, E0_IDX, k, rep);
                const _Float16* A0 = (k == 0) ? (hz + (size_t)r*HID + kofs)
                                              : (h0ring + (size_t)(k-1)*BH + (size_t)r*HID + kofs);
                gemm_asm_ldsb(A0, wfrag, acc);
            }

            #pragma unroll
            for (int mt = 0; mt < 4; ++mt)
                #pragma unroll
                for (int j = 0; j < 4; ++j)
                    accL[wv][mt*16 + q*4 + j][r] = acc[mt][j];
            __syncthreads();

            // elementwise: 1 output/thread; col = wv, row = lane
            f32x4 z = bias;
            #pragma unroll
            for (int w2 = 0; w2 < 4; ++w2){
                f32x4 a = *reinterpret_cast<const f32x4*>(&accL[w2][lane][wv*4]);
                z.x += a.x; z.y += a.y; z.z += a.z; z.w += a.w;
            }
            float c = sigm_f(z.y)*cst + sigm_f(z.x)*tanh_f(z.z);
            cst = c;
            _Float16 hh = (_Float16)(sigm_f(z.w) * tanh_f(c));
            unsigned hb = (unsigned)__builtin_bit_cast(unsigned short, hh);
            store_h2(h0ring + ((size_t)k*BATCH + lane)*HID + wgl*4 + wv, hb);
            drain_vmem();
            __syncthreads();
            if (tid == 0)
                __hip_atomic_store(&flags[F0_BASE + wgl*32], k + 1,
                                   __ATOMIC_RELAXED, __HIP_MEMORY_SCOPE_AGENT);
        }
        return;
    }

    // ==================== LAYER 1 ====================
    const char* wfrag = smem + (wv >= 1 ? (wv-1)*16384 : 0) + lane*16;  // wv1,2,3 regions
    for (int k = 1; k <= SEQ; ++k){
        const int t1 = k - 1;
        f32x4 acc[4];
        #pragma unroll
        for (int m = 0; m < 4; ++m){ acc[m].x=0;acc[m].y=0;acc[m].z=0;acc[m].w=0; }

        if (wv < 2){
            // input projection: A = h0[k-1], K-half per wave
            if (wv == 0 && wgl == 0) aggregate_publish(flags, F0_BASE, E0_IDX, k, lane);
            else                     wait_epoch_g(flags, E0_IDX, k, rep);
            const _Float16* A = h0ring + (size_t)(k-1)*BH + (size_t)r*HID + kofs;
            if (wv == 0)
                gemm_asm_gb(A, Wr1 + (size_t)(p0 + r)*KCAT + q*8, acc);   // cols 0..511 global
            else
                gemm_asm_ldsb(A, wfrag, acc);                              // cols 512..1023 LDS
        } else {
            // recurrent: A = h1[k-2] (or hz at k=1)
            if (k >= 2){
                if (wv == 2 && wgl == 1) aggregate_publish(flags, F1_BASE, E1_IDX, k-1, lane);
                else                     wait_epoch_g(flags, E1_IDX, k-1, rep);
            }
            const _Float16* A = (k == 1) ? (hz + (size_t)r*HID + kofs)
                                         : (h1ring + (size_t)(k-2)*BH + (size_t)r*HID + kofs);
            gemm_asm_ldsb(A, wfrag, acc);
        }

        #pragma unroll
        for (int mt = 0; mt < 4; ++mt)
            #pragma unroll
            for (int j = 0; j < 4; ++j)
                accL[wv][mt*16 + q*4 + j][r] = acc[mt][j];
        __syncthreads();

        f32x4 z = bias;
        #pragma unroll
        for (int w2 = 0; w2 < 4; ++w2){
            f32x4 a = *reinterpret_cast<const f32x4*>(&accL[w2][lane][wv*4]);
            z.x += a.x; z.y += a.y; z.z += a.z; z.w += a.w;
        }
        float c = sigm_f(z.y)*cst + sigm_f(z.x)*tanh_f(z.z);
        cst = c;
        float h = sigm_f(z.w) * tanh_f(c);
        _Float16 hh = (_Float16)h;
        unsigned hb = (unsigned)__builtin_bit_cast(unsigned short, hh);
        store_h2(h1ring + ((size_t)t1*BATCH + lane)*HID + wgl*4 + wv, hb);
        if (t1 < SEQ-1) out[((size_t)t1*BATCH + lane)*HID + wgl*4 + wv] = h;
        else            ho_keep = h;            // out[511] deferred (alias safety)
        drain_vmem();
        __syncthreads();
        if (tid == 0)
            __hip_atomic_store(&flags[F1_BASE + wgl*32], k,
                               __ATOMIC_RELAXED, __HIP_MEMORY_SCOPE_AGENT);
    }

    // epilogue: out[511] after ALL layer1 wgs finished round-512 h0 reads
    if (wgl == 1 && wv == 2) aggregate_publish(flags, F1_BASE, E1_IDX, SEQ, lane);
    wait_epoch_g(flags, E1_IDX, SEQ, rep);
    out[((size_t)(SEQ-1)*BATCH + lane)*HID + wgl*4 + wv] = ho_keep;
}

// ---------------- host launcher ----------------

extern "C" void kernel_launch(void* const* d_in, const int* in_sizes, int n_in,
                              void* d_out, int out_size, void* d_ws, size_t ws_size,
                              hipStream_t stream){
    const float* x   = (const float*)d_in[0];
    const float* Wx0 = (const float*)d_in[1];
    const float* bx0 = (const float*)d_in[2];
    const float* Wh0 = (const float*)d_in[3];
    const float* bh0 = (const float*)d_in[4];
    const float* Wx1 = (const float*)d_in[5];
    const float* bx1 = (const float*)d_in[6];
    const float* Wh1 = (const float*)d_in[7];
    const float* bh1 = (const float*)d_in[8];
    float* out = (float*)d_out;
    char* ws = (char*)d_ws;

    size_t o = 0;
    _Float16* Wr0 = (_Float16*)(ws + o); o += (size_t)NG*KCAT*2;
    _Float16* Wr1 = (_Float16*)(ws + o); o += (size_t)NG*KCAT*2;
    float* br0 = (float*)(ws + o); o += 16384;
    float* br1 = (float*)(ws + o); o += 16384;
    _Float16* h1ring = (_Float16*)(ws + o); o += (size_t)SEQ*BATCH*HID*2;
    _Float16* hz     = (_Float16*)(ws + o); o += (size_t)BATCH*HID*2;
    int* flags = (int*)(ws + o); o += 131072;

    const size_t RING = (size_t)SEQ*BATCH*HID*2;
    _Float16 *xbf = nullptr, *h0ring;
    int use_xf16 = 0;
    if (ws_size >= o + 2*RING){
        xbf    = (_Float16*)(ws + o);  o += RING;  use_xf16 = 1;
        h0ring = (_Float16*)(ws + o);  o += RING;
    } else if (ws_size >= o + RING){
        xbf    = (_Float16*)(ws + o);  o += RING;  use_xf16 = 1;
        h0ring = (_Float16*)((char*)d_out + (size_t)64*1024*1024);
    } else {
        h0ring = (_Float16*)((char*)d_out + (size_t)64*1024*1024);
    }

    hipFuncSetAttribute((const void*)lstm_persist,
                        hipFuncAttributeMaxDynamicSharedMemorySize, SMEM_BYTES);

    prep_w_kernel<<<NG, 256, 0, stream>>>(Wx0, Wh0, bx0, bh0, Wr0, br0);
    prep_w_kernel<<<NG, 256, 0, stream>>>(Wx1, Wh1, bx1, bh1, Wr1, br1);
    if (use_xf16)
        prep_x_kernel<<<(SEQ*BATCH*HID)/(256*8), 256, 0, stream>>>(x, xbf);
    init_misc_kernel<<<128, 256, 0, stream>>>(flags, hz);
    lstm_persist<<<512, 256, SMEM_BYTES, stream>>>(Wr0, Wr1, br0, br1, xbf, x, use_xf16,
                                                   hz, h0ring, h1ring, out, flags);
}

// Round 16
// 9279.263 us; speedup vs baseline: 1.0697x; 1.0697x over previous
//
#include <hip/hip_runtime.h>

// LSTM 2-layer, S=512 B=64 IN=H=1024, fp32 I/O, fp16 MFMA compute.
// R16 = R14 (best, 8.76ms) + CONTINUOUS epoch aggregation:
//   All wgs 320 threads. wv4 joins the regular __syncthreads (R12's bar4
//   substitution was its regression, not the comms-wave concept).
//   wg0/wv4 polls flags0/flags1 and publishes epoch0/epoch1 replicas
//   CONTINUOUSLY inside each phase window (gated by an LDS marker wv3
//   writes right before each barrier) -> epochs publish the moment the
//   slowest producer flag lands, mid-phase, instead of at the top of
//   wg0's next phase (R14's ~4-5us/round aggregation lag + skew
//   re-absorption). wg!=0 wv4 only mirrors the barrier count.
// Compute waves identical to R14 (two-phase merged round, asm-MLP 32-flight
// GEMM banks, frag-ordered weight LDS, sc0|sc1 h rings, relaxed flags, no
// fences); in-loop aggregate_publish calls removed (wv4 owns publishing).

#define SEQ   512
#define BATCH 64
#define HID   1024
#define NG    4096
#define KCAT  2048
#define F0_BASE 0            // flags0: + wg*32
#define E0_IDX  8192         // epoch0 replicas: + (wg&31)*32
#define F1_BASE 16384        // flags1: + wg*32
#define E1_IDX  24576        // epoch1 replicas: + (wg&31)*32

// dynamic LDS (bytes):
//   [0,32768)       Wh0 frag-ordered
//   [32768,98304)   W1  frag-ordered
//   [98304,133120)  accL: float[2][4][64][17]
//   [133120,133124) phase marker (wv3 -> wv4)
#define MARK_OFF 133120
#define SMEM_BYTES 133184

typedef __attribute__((ext_vector_type(8))) _Float16 f16x8;
typedef __attribute__((ext_vector_type(4))) _Float16 f16x4;
typedef __attribute__((ext_vector_type(4))) float    f32x4;

__device__ __forceinline__ float sigm_f(float x){ return 1.f/(1.f + __expf(-x)); }
__device__ __forceinline__ float tanh_f(float x){
    float e = __expf(-2.f*fabsf(x));
    float r = (1.f - e)/(1.f + e);
    return copysignf(r, x);
}

__device__ __forceinline__ void store_h8(_Float16* p, f16x4 v){
    asm volatile("global_store_dwordx2 %0, %1, off sc0 sc1" :: "v"(p), "v"(v) : "memory");
}
__device__ __forceinline__ void drain_vmem(){
    asm volatile("s_waitcnt vmcnt(0)" ::: "memory");
}

// ---- ordered asm loads (R14-verified) ----
#define GLD(dst, base, OFF) \
    asm volatile("global_load_dwordx4 %0, %1, off offset:" #OFF \
                 : "=&v"(dst) : "v"(base))
#define GLD8L(arr, i, B) \
    GLD(arr[(i)+0],B,0);   GLD(arr[(i)+1],B,64);  GLD(arr[(i)+2],B,128); GLD(arr[(i)+3],B,192); \
    GLD(arr[(i)+4],B,256); GLD(arr[(i)+5],B,320); GLD(arr[(i)+6],B,384); GLD(arr[(i)+7],B,448)
#define GLD8H(arr, i, B) \
    GLD(arr[(i)+0],B,512); GLD(arr[(i)+1],B,576); GLD(arr[(i)+2],B,640); GLD(arr[(i)+3],B,704); \
    GLD(arr[(i)+4],B,768); GLD(arr[(i)+5],B,832); GLD(arr[(i)+6],B,896); GLD(arr[(i)+7],B,960)
#define VMWAIT0 \
    asm volatile("s_waitcnt vmcnt(0)" ::: "memory"); \
    __builtin_amdgcn_sched_barrier(0)

// ---------------- prep kernels ----------------

__global__ void prep_w_kernel(const float* __restrict__ Wx, const float* __restrict__ Wh,
                              const float* __restrict__ bx, const float* __restrict__ bh,
                              _Float16* __restrict__ Wr, float* __restrict__ br){
    int p = blockIdx.x;
    int j = p >> 2, g = p & 3;
    int r = g*1024 + j;
    int k = threadIdx.x * 8;
    const float* s = (k < 1024) ? (Wx + (size_t)r*1024 + k)
                                : (Wh + (size_t)r*1024 + (k - 1024));
    float4 v0 = *reinterpret_cast<const float4*>(s);
    float4 v1 = *reinterpret_cast<const float4*>(s + 4);
    f16x8 o;
    o[0]=(_Float16)v0.x; o[1]=(_Float16)v0.y; o[2]=(_Float16)v0.z; o[3]=(_Float16)v0.w;
    o[4]=(_Float16)v1.x; o[5]=(_Float16)v1.y; o[6]=(_Float16)v1.z; o[7]=(_Float16)v1.w;
    *reinterpret_cast<f16x8*>(Wr + (size_t)p*KCAT + k) = o;
    if (threadIdx.x == 0) br[p] = bx[r] + bh[r];
}

__global__ void prep_x_kernel(const float* __restrict__ x, _Float16* xo){
    size_t i = ((size_t)blockIdx.x*256 + threadIdx.x) * 8;
    float4 v0 = *reinterpret_cast<const float4*>(x + i);
    float4 v1 = *reinterpret_cast<const float4*>(x + i + 4);
    f16x8 o;
    o[0]=(_Float16)v0.x; o[1]=(_Float16)v0.y; o[2]=(_Float16)v0.z; o[3]=(_Float16)v0.w;
    o[4]=(_Float16)v1.x; o[5]=(_Float16)v1.y; o[6]=(_Float16)v1.z; o[7]=(_Float16)v1.w;
    *reinterpret_cast<f16x8*>(xo + i) = o;
}

__global__ void init_misc_kernel(int* flags, _Float16* hz){
    int i = blockIdx.x*256 + threadIdx.x;            // 32768 threads
    flags[i] = 0;
    if (i < 16384){
        f16x4 z; z[0]=(_Float16)0.f; z[1]=(_Float16)0.f; z[2]=(_Float16)0.f; z[3]=(_Float16)0.f;
        *reinterpret_cast<f16x4*>(hz + (size_t)i*4) = z;
    }
}

// ---------------- sync helpers (no fences) ----------------

__device__ __forceinline__ int gload(const int* p){
    return __hip_atomic_load(p, __ATOMIC_RELAXED, __HIP_MEMORY_SCOPE_AGENT);
}
__device__ __forceinline__ void gstore(int* p, int v){
    __hip_atomic_store(p, v, __ATOMIC_RELAXED, __HIP_MEMORY_SCOPE_AGENT);
}

__device__ __forceinline__ void wait_epoch_g(const int* flags, int eidx, int k, int rep){
    for(;;){
        int e = gload(&flags[eidx + rep*32]);
        if (e >= k) break;
        __builtin_amdgcn_s_sleep(2);
    }
    asm volatile("" ::: "memory");
}

__device__ __forceinline__ void aggregate_publish(int* flags, int base, int eidx,
                                                  int k, int lane){
    const int b = lane*4;
    for(;;){
        int a0 = gload(&flags[base + (b+0)*32]);
        int a1 = gload(&flags[base + (b+1)*32]);
        int a2 = gload(&flags[base + (b+2)*32]);
        int a3 = gload(&flags[base + (b+3)*32]);
        bool ok = (a0>=k) && (a1>=k) && (a2>=k) && (a3>=k);
        if (__all(ok)) break;
        __builtin_amdgcn_s_sleep(1);
    }
    asm volatile("" ::: "memory");
    if (lane < 32)
        gstore(&flags[eidx + lane*32], k);
}

__device__ __forceinline__ int wave_min_i(int v){
    #pragma unroll
    for (int off = 1; off < 64; off <<= 1)
        v = min(v, __shfl_xor(v, off));
    return v;
}

// one scan of all 256+256 flags; publish any epoch improvement (monotone)
__device__ __forceinline__ void scan_publish(int* flags, int lane, int& pub0, int& pub1){
    int f0 = 0x7fffffff, f1 = 0x7fffffff;
    #pragma unroll
    for (int j = 0; j < 4; ++j){
        int i4 = lane*4 + j;
        f0 = min(f0, gload(&flags[F0_BASE + i4*32]));
        f1 = min(f1, gload(&flags[F1_BASE + i4*32]));
    }
    int m0 = wave_min_i(f0), m1 = wave_min_i(f1);
    if (m0 > pub0){ if (lane < 32) gstore(&flags[E0_IDX + lane*32], m0); pub0 = m0; }
    if (m1 > pub1){ if (lane < 32) gstore(&flags[E1_IDX + lane*32], m1); pub1 = m1; }
}

// poll+publish until the wg's compute waves reach the next barrier (marker)
__device__ __forceinline__ void agg_window(int* flags, int* mark, int tgt,
                                           int& pub0, int& pub1, int lane){
    while (__hip_atomic_load(mark, __ATOMIC_RELAXED, __HIP_MEMORY_SCOPE_WORKGROUP) < tgt){
        scan_publish(flags, lane, pub0, pub1);
        __builtin_amdgcn_s_sleep(1);
    }
    scan_publish(flags, lane, pub0, pub1);   // final scan before joining barrier
    asm volatile("" ::: "memory");
}

// ---------------- GEMM helpers (R14-verified) ----------------

__device__ __forceinline__ f32x4 mfma16(f16x8 a, f16x8 b, f32x4 c){
    return __builtin_amdgcn_mfma_f32_16x16x32_f16(a, b, c, 0, 0, 0);
}

__device__ __forceinline__ void gemm_asm_ldsb(const _Float16* A, const char* wfrag,
                                              f32x4* acc){
    const _Float16* b0 = A;
    const _Float16* b1 = A + 16*1024;
    const _Float16* b2 = A + 32*1024;
    const _Float16* b3 = A + 48*1024;
    f16x8 a[32];
    __builtin_amdgcn_sched_barrier(0);
    GLD8L(a, 0, b0); GLD8L(a, 8, b1); GLD8L(a, 16, b2); GLD8L(a, 24, b3);
    VMWAIT0;
    #pragma unroll
    for (int kk = 0; kk < 8; ++kk){
        f16x8 bb = *reinterpret_cast<const f16x8*>(wfrag + kk*1024);
        acc[0] = mfma16(a[kk],      bb, acc[0]);
        acc[1] = mfma16(a[8 + kk],  bb, acc[1]);
        acc[2] = mfma16(a[16 + kk], bb, acc[2]);
        acc[3] = mfma16(a[24 + kk], bb, acc[3]);
    }
    __builtin_amdgcn_sched_barrier(0);
    GLD8H(a, 0, b0); GLD8H(a, 8, b1); GLD8H(a, 16, b2); GLD8H(a, 24, b3);
    VMWAIT0;
    #pragma unroll
    for (int kk = 0; kk < 8; ++kk){
        f16x8 bb = *reinterpret_cast<const f16x8*>(wfrag + (8 + kk)*1024);
        acc[0] = mfma16(a[kk],      bb, acc[0]);
        acc[1] = mfma16(a[8 + kk],  bb, acc[1]);
        acc[2] = mfma16(a[16 + kk], bb, acc[2]);
        acc[3] = mfma16(a[24 + kk], bb, acc[3]);
    }
    __builtin_amdgcn_sched_barrier(0);
}

__device__ __forceinline__ void gemm_asm_gb(const _Float16* A, const _Float16* Wp,
                                            f32x4* acc){
    const _Float16* b0 = A;
    const _Float16* b1 = A + 16*1024;
    const _Float16* b2 = A + 32*1024;
    const _Float16* b3 = A + 48*1024;
    f16x8 bw[8], a[32];
    __builtin_amdgcn_sched_barrier(0);
    GLD8L(bw, 0, Wp);
    GLD8L(a, 0, b0); GLD8L(a, 8, b1); GLD8L(a, 16, b2); GLD8L(a, 24, b3);
    VMWAIT0;
    #pragma unroll
    for (int kk = 0; kk < 8; ++kk){
        acc[0] = mfma16(a[kk],      bw[kk], acc[0]);
        acc[1] = mfma16(a[8 + kk],  bw[kk], acc[1]);
        acc[2] = mfma16(a[16 + kk], bw[kk], acc[2]);
        acc[3] = mfma16(a[24 + kk], bw[kk], acc[3]);
    }
    __builtin_amdgcn_sched_barrier(0);
    GLD8H(bw, 0, Wp);
    GLD8H(a, 0, b0); GLD8H(a, 8, b1); GLD8H(a, 16, b2); GLD8H(a, 24, b3);
    VMWAIT0;
    #pragma unroll
    for (int kk = 0; kk < 8; ++kk){
        acc[0] = mfma16(a[kk],      bw[kk], acc[0]);
        acc[1] = mfma16(a[8 + kk],  bw[kk], acc[1]);
        acc[2] = mfma16(a[16 + kk], bw[kk], acc[2]);
        acc[3] = mfma16(a[24 + kk], bw[kk], acc[3]);
    }
    __builtin_amdgcn_sched_barrier(0);
}

__device__ __forceinline__ void gemm_q_f32(const float* A, const _Float16* Wp, f32x4* acc){
    #pragma unroll 2
    for (int kk = 0; kk < 16; ++kk){
        f16x8 b = *reinterpret_cast<const f16x8*>(Wp + kk*32);
        f16x8 a[4];
        #pragma unroll
        for (int m = 0; m < 4; ++m){
            float4 u0 = *reinterpret_cast<const float4*>(A + kk*32 + (size_t)m*16*1024);
            float4 u1 = *reinterpret_cast<const float4*>(A + kk*32 + (size_t)m*16*1024 + 4);
            f16x8 v;
            v[0]=(_Float16)u0.x; v[1]=(_Float16)u0.y; v[2]=(_Float16)u0.z; v[3]=(_Float16)u0.w;
            v[4]=(_Float16)u1.x; v[5]=(_Float16)u1.y; v[6]=(_Float16)u1.z; v[7]=(_Float16)u1.w;
            a[m] = v;
        }
        acc[0] = mfma16(a[0], b, acc[0]);
        acc[1] = mfma16(a[1], b, acc[1]);
        acc[2] = mfma16(a[2], b, acc[2]);
        acc[3] = mfma16(a[3], b, acc[3]);
    }
}

// ---------------- persistent LSTM kernel ----------------

__global__ __launch_bounds__(320, 1)
void lstm_persist(const _Float16* __restrict__ Wr0, const _Float16* __restrict__ Wr1,
                  const float* __restrict__ br0, const float* __restrict__ br1,
                  const _Float16* __restrict__ xbf, const float* __restrict__ xf32,
                  int use_xf16, const _Float16* __restrict__ hz,
                  _Float16* h0ring, _Float16* h1ring, float* out, int* flags){
    extern __shared__ char smem[];
    float (*accL)[4][64][17] = reinterpret_cast<float(*)[4][64][17]>(smem + 98304);
    int* mark = reinterpret_cast<int*>(smem + MARK_OFF);

    const int tid  = threadIdx.x;
    const int wg   = blockIdx.x;
    const int wv   = tid >> 6;            // 0..4 (wv4 = comms/barrier-mirror)
    const int lane = tid & 63;
    const int r    = lane & 15;
    const int q    = lane >> 4;
    const int p0   = wg * 16;
    const int rep  = wg & 31;

    // stage recurrent-path weights, FRAG-ORDERED (all 320 threads)
    for (int idx = tid; idx < 6144; idx += 320){
        const _Float16* s; char* dst;
        if (idx < 2048){                     // Wh0
            int wvh = idx >> 10, kk = (idx >> 6) & 15, ln = idx & 63;
            s = Wr0 + (size_t)(p0 + (ln & 15))*KCAT + 1024 + wvh*512 + kk*32 + (ln >> 4)*8;
            dst = smem + idx*16;
        } else {                             // W1
            int d = idx - 2048;
            int wvd = d >> 10, kk = (d >> 6) & 15, ln = d & 63;
            s = Wr1 + (size_t)(p0 + (ln & 15))*KCAT + wvd*512 + kk*32 + (ln >> 4)*8;
            dst = smem + 32768 + d*16;
        }
        *reinterpret_cast<f16x8*>(dst) = *reinterpret_cast<const f16x8*>(s);
    }
    if (tid == 0) *mark = 0;
    __syncthreads();

    // ================= comms wave (barrier-mirrored) =================
    if (wv == 4){
        if (wg == 0){
            int pub0 = 0, pub1 = 0;
            for (int k = 0; k <= SEQ; ++k){
                agg_window(flags, mark, 2*k + 1, pub0, pub1, lane);
                __syncthreads();   // SYNC_A
                agg_window(flags, mark, 2*k + 2, pub0, pub1, lane);
                __syncthreads();   // SYNC_B
            }
            // epilogue: blocking aggregate of flag0 = SEQ+1, publish
            aggregate_publish(flags, F0_BASE, E0_IDX, SEQ + 1, lane);
        } else {
            for (int k = 0; k <= SEQ; ++k){
                __syncthreads();
                __syncthreads();
            }
        }
        return;
    }

    // ================= compute waves (wv0-3, R14 logic) =================
    f32x4 cst = {0.f,0.f,0.f,0.f};
    f32x4 ho_keep = {0.f,0.f,0.f,0.f};
    f32x4 bias[4];
    {
        const float* bsrc = (wv == 0) ? br0 : br1;
        #pragma unroll
        for (int jj = 0; jj < 4; ++jj)
            bias[jj] = *reinterpret_cast<const f32x4*>(&bsrc[p0 + jj*4]);
    }

    const int kofs = (wv & 1)*512 + q*8;
    const int wcol = wv*512 + q*8;
    const char* wh0frag = smem + (wv >= 2 ? (wv-2)*16384 : 0) + lane*16;
    const char* w1frag  = smem + 32768 + wv*16384 + lane*16;
    const size_t BH = (size_t)BATCH*HID;

    for (int k = 0; k <= SEQ; ++k){
        // ---------------- PHASE 1 ----------------
        f32x4 acc[4];
        #pragma unroll
        for (int m = 0; m < 4; ++m){ acc[m].x=0;acc[m].y=0;acc[m].z=0;acc[m].w=0; }

        if (wv < 2){
            if (k < SEQ){
                if (use_xf16)
                    gemm_asm_gb(xbf + (size_t)k*BH + (size_t)r*HID + kofs,
                                Wr0 + (size_t)(p0 + r)*KCAT + wcol, acc);
                else
                    gemm_q_f32(xf32 + (size_t)k*BH + (size_t)r*HID + kofs,
                               Wr0 + (size_t)(p0 + r)*KCAT + wcol, acc);
            }
        } else {
            if (k > 0) wait_epoch_g(flags, E0_IDX, k, rep);   // pre-published by wv4
            if (k < SEQ){
                const _Float16* A0 = (k == 0) ? (hz + (size_t)r*HID + kofs)
                                              : (h0ring + (size_t)(k-1)*BH + (size_t)r*HID + kofs);
                gemm_asm_ldsb(A0, wh0frag, acc);
            }
        }

        #pragma unroll
        for (int mt = 0; mt < 4; ++mt)
            #pragma unroll
            for (int j = 0; j < 4; ++j)
                accL[0][wv][mt*16 + q*4 + j][r] = acc[mt][j];
        if (wv == 3 && lane == 0)
            __hip_atomic_store(mark, 2*k + 1, __ATOMIC_RELAXED, __HIP_MEMORY_SCOPE_WORKGROUP);
        __syncthreads();   // SYNC_A

        if (wv == 0 && k < SEQ){
            f32x4 zz[4];
            #pragma unroll
            for (int jj = 0; jj < 4; ++jj) zz[jj] = bias[jj];
            #pragma unroll
            for (int w2 = 0; w2 < 4; ++w2)
                #pragma unroll
                for (int jj = 0; jj < 4; ++jj){
                    f32x4 a = *reinterpret_cast<const f32x4*>(&accL[0][w2][lane][jj*4]);
                    zz[jj].x += a.x; zz[jj].y += a.y; zz[jj].z += a.z; zz[jj].w += a.w;
                }
            f16x4 hv;
            #pragma unroll
            for (int jl = 0; jl < 4; ++jl){
                float ig = sigm_f(zz[jl].x), fg = sigm_f(zz[jl].y);
                float gg = tanh_f(zz[jl].z), og = sigm_f(zz[jl].w);
                float c = fg*cst[jl] + ig*gg;  cst[jl] = c;
                hv[jl] = (_Float16)(og * tanh_f(c));
            }
            store_h8(h0ring + ((size_t)k*BATCH + lane)*HID + wg*4, hv);
            drain_vmem();
            if (lane == 0) gstore(&flags[F0_BASE + wg*32], k + 1);
        }

        // ---------------- PHASE 2 ----------------
        #pragma unroll
        for (int m = 0; m < 4; ++m){ acc[m].x=0;acc[m].y=0;acc[m].z=0;acc[m].w=0; }

        if (k >= 1){
            if (wv < 2){
                // SYNC_A implies epoch0 >= k (wv2/3 observed it) -> no wait
                gemm_asm_ldsb(h0ring + (size_t)(k-1)*BH + (size_t)r*HID + kofs,
                              w1frag, acc);
            } else {
                if (k >= 2) wait_epoch_g(flags, E1_IDX, k-1, rep);  // pre-published
                const _Float16* A1 = (k == 1) ? (hz + (size_t)r*HID + kofs)
                                              : (h1ring + (size_t)(k-2)*BH + (size_t)r*HID + kofs);
                gemm_asm_ldsb(A1, w1frag, acc);
            }
        }

        #pragma unroll
        for (int mt = 0; mt < 4; ++mt)
            #pragma unroll
            for (int j = 0; j < 4; ++j)
                accL[1][wv][mt*16 + q*4 + j][r] = acc[mt][j];
        if (wv == 3 && lane == 0)
            __hip_atomic_store(mark, 2*k + 2, __ATOMIC_RELAXED, __HIP_MEMORY_SCOPE_WORKGROUP);
        __syncthreads();   // SYNC_B

        if (wv == 1 && k >= 1){
            const int t1 = k - 1;
            f32x4 zz[4];
            #pragma unroll
            for (int jj = 0; jj < 4; ++jj) zz[jj] = bias[jj];
            #pragma unroll
            for (int w2 = 0; w2 < 4; ++w2)
                #pragma unroll
                for (int jj = 0; jj < 4; ++jj){
                    f32x4 a = *reinterpret_cast<const f32x4*>(&accL[1][w2][lane][jj*4]);
                    zz[jj].x += a.x; zz[jj].y += a.y; zz[jj].z += a.z; zz[jj].w += a.w;
                }
            f16x4 hv; f32x4 ho;
            #pragma unroll
            for (int jl = 0; jl < 4; ++jl){
                float ig = sigm_f(zz[jl].x), fg = sigm_f(zz[jl].y);
                float gg = tanh_f(zz[jl].z), og = sigm_f(zz[jl].w);
                float c = fg*cst[jl] + ig*gg;  cst[jl] = c;
                float h = og * tanh_f(c);
                hv[jl] = (_Float16)h;  ho[jl] = h;
            }
            if (k < SEQ) store_h8(h1ring + ((size_t)t1*BATCH + lane)*HID + wg*4, hv);
            if (t1 < SEQ-1) *reinterpret_cast<f32x4*>(out + ((size_t)t1*BATCH + lane)*HID + wg*4) = ho;
            else            ho_keep = ho;   // out[511] deferred (alias safety)
            drain_vmem();
            if (lane == 0) gstore(&flags[F1_BASE + wg*32], k);
        }
    }

    // epilogue: flag0=SEQ+1 after all local reads of h0[511]; wv4-wg0 publishes
    if (tid == 0) gstore(&flags[F0_BASE + wg*32], SEQ + 1);
    if (wv == 1){
        wait_epoch_g(flags, E0_IDX, SEQ + 1, rep);
        *reinterpret_cast<f32x4*>(out + ((size_t)(SEQ-1)*BATCH + lane)*HID + wg*4) = ho_keep;
    }
}

// ---------------- host launcher ----------------

extern "C" void kernel_launch(void* const* d_in, const int* in_sizes, int n_in,
                              void* d_out, int out_size, void* d_ws, size_t ws_size,
                              hipStream_t stream){
    const float* x   = (const float*)d_in[0];
    const float* Wx0 = (const float*)d_in[1];
    const float* bx0 = (const float*)d_in[2];
    const float* Wh0 = (const float*)d_in[3];
    const float* bh0 = (const float*)d_in[4];
    const float* Wx1 = (const float*)d_in[5];
    const float* bx1 = (const float*)d_in[6];
    const float* Wh1 = (const float*)d_in[7];
    const float* bh1 = (const float*)d_in[8];
    float* out = (float*)d_out;
    char* ws = (char*)d_ws;

    size_t o = 0;
    _Float16* Wr0 = (_Float16*)(ws + o); o += (size_t)NG*KCAT*2;
    _Float16* Wr1 = (_Float16*)(ws + o); o += (size_t)NG*KCAT*2;
    float* br0 = (float*)(ws + o); o += 16384;
    float* br1 = (float*)(ws + o); o += 16384;
    _Float16* h1ring = (_Float16*)(ws + o); o += (size_t)SEQ*BATCH*HID*2;
    _Float16* hz     = (_Float16*)(ws + o); o += (size_t)BATCH*HID*2;
    int* flags = (int*)(ws + o); o += 131072;

    const size_t RING = (size_t)SEQ*BATCH*HID*2;
    _Float16 *xbf = nullptr, *h0ring;
    int use_xf16 = 0;
    if (ws_size >= o + 2*RING){
        xbf    = (_Float16*)(ws + o);  o += RING;  use_xf16 = 1;
        h0ring = (_Float16*)(ws + o);  o += RING;
    } else if (ws_size >= o + RING){
        xbf    = (_Float16*)(ws + o);  o += RING;  use_xf16 = 1;
        h0ring = (_Float16*)((char*)d_out + (size_t)64*1024*1024);
    } else {
        h0ring = (_Float16*)((char*)d_out + (size_t)64*1024*1024);
    }

    hipFuncSetAttribute((const void*)lstm_persist,
                        hipFuncAttributeMaxDynamicSharedMemorySize, SMEM_BYTES);

    prep_w_kernel<<<NG, 256, 0, stream>>>(Wx0, Wh0, bx0, bh0, Wr0, br0);
    prep_w_kernel<<<NG, 256, 0, stream>>>(Wx1, Wh1, bx1, bh1, Wr1, br1);
    if (use_xf16)
        prep_x_kernel<<<(SEQ*BATCH*HID)/(256*8), 256, 0, stream>>>(x, xbf);
    init_misc_kernel<<<128, 256, 0, stream>>>(flags, hz);
    lstm_persist<<<256, 320, SMEM_BYTES, stream>>>(Wr0, Wr1, br0, br1, xbf, x, use_xf16,
                                                   hz, h0ring, h1ring, out, flags);
}